// Round 11
// baseline (460.992 us; speedup 1.0000x reference)
//
#include <hip/hip_runtime.h>

// Cayley map: R = (I+A)(I-A)^{-1} = ((1-s)I + 2A + 2 v v^T)/(1+s), s=|v|^2.
// N = 4e6 fp32 points. Memory-bound: 48 MB read + 144 MB write -> ~31 us roofline.
// 8 points/thread => 6x float4 nt-loads, 18x float4 nt-stores; wave covers
// 18432 B contiguous output. Kernel proven < 84 us (absent from top-5 vs 84-us
// harness fills in R8); this round tests whether store-path slack remains.
// NOTE: __builtin_nontemporal_* needs a clang ext_vector_type, not HIP float4.

typedef float f4 __attribute__((ext_vector_type(4)));

__device__ __forceinline__ void cayley(float x, float y, float z, float* m) {
    float s   = x * x + y * y + z * z;
    float inv = 1.0f / (1.0f + s);
    float d   = 1.0f - s;
    m[0] = (d + 2.0f * x * x) * inv;
    m[1] = (2.0f * (x * y - z)) * inv;
    m[2] = (2.0f * (x * z + y)) * inv;
    m[3] = (2.0f * (x * y + z)) * inv;
    m[4] = (d + 2.0f * y * y) * inv;
    m[5] = (2.0f * (y * z - x)) * inv;
    m[6] = (2.0f * (x * z - y)) * inv;
    m[7] = (2.0f * (y * z + x)) * inv;
    m[8] = (d + 2.0f * z * z) * inv;
}

extern "C" __global__ __launch_bounds__(256)
void cayley_kernel(const float* __restrict__ t, float* __restrict__ out, int npts) {
    const int tid = blockIdx.x * 256 + threadIdx.x;
    const long p0 = (long)tid * 8;
    if (p0 + 8 <= npts) {
        // 24 consecutive floats = points p0..p0+7
        const f4* in4 = (const f4*)t + (size_t)tid * 6;
        float f[24];
        #pragma unroll
        for (int i = 0; i < 6; ++i) {
            f4 v = __builtin_nontemporal_load(in4 + i);
            f[4 * i + 0] = v.x; f[4 * i + 1] = v.y;
            f[4 * i + 2] = v.z; f[4 * i + 3] = v.w;
        }
        f4* o4 = (f4*)out + (size_t)tid * 18;
        // two halves of 4 points each to cap register liveness (~80 VGPR)
        #pragma unroll
        for (int h = 0; h < 2; ++h) {
            float m[36];
            #pragma unroll
            for (int i = 0; i < 4; ++i) {
                const int p = 4 * h + i;
                cayley(f[3 * p + 0], f[3 * p + 1], f[3 * p + 2], &m[9 * i]);
            }
            #pragma unroll
            for (int k = 0; k < 9; ++k) {
                f4 v;
                v.x = m[4 * k + 0]; v.y = m[4 * k + 1];
                v.z = m[4 * k + 2]; v.w = m[4 * k + 3];
                __builtin_nontemporal_store(v, o4 + 9 * h + k);
            }
        }
    } else if (p0 < npts) {
        // tail (not hit for N=4e6: 4M/8 = 500k threads exactly)
        for (long p = p0; p < npts; ++p) {
            float mm[9];
            cayley(t[3 * p + 0], t[3 * p + 1], t[3 * p + 2], mm);
            for (int k = 0; k < 9; ++k) out[9 * p + k] = mm[k];
        }
    }
}

extern "C" void kernel_launch(void* const* d_in, const int* in_sizes, int n_in,
                              void* d_out, int out_size, void* d_ws, size_t ws_size,
                              hipStream_t stream) {
    const float* t = (const float*)d_in[0];
    float* out = (float*)d_out;
    const int npts = in_sizes[0] / 3;
    const int nthreads = (npts + 7) / 8;
    const int blocks = (nthreads + 255) / 256;
    cayley_kernel<<<blocks, 256, 0, stream>>>(t, out, npts);
}

// Round 14
// 179.723 us; speedup vs baseline: 2.5650x; 2.5650x over previous
//
#include <hip/hip_runtime.h>

// Cayley map: R = ((1-s)I + 2A + 2 v v^T)/(1+s), s=|v|^2. N=4e6 fp32 points.
// Memory-bound: 48 MB read + 144 MB write -> ~31 us roofline @ 6.3 TB/s.
// R11 lesson: per-thread 16B nt stores at 288B lane stride bypass L2 merge ->
// 2.9x write amplification (WRITE_SIZE 417 MB), 336 us. Fix: LDS-stage the
// block's output (36 KB) and store with lane-consecutive float4 -> each wave
// store instruction covers 4 KB contiguous (full sectors, no RMW, nt safe).

typedef float f4 __attribute__((ext_vector_type(4)));

__device__ __forceinline__ void cayley(float x, float y, float z, float* m) {
    float s   = x * x + y * y + z * z;
    float inv = 1.0f / (1.0f + s);
    float d   = 1.0f - s;
    m[0] = (d + 2.0f * x * x) * inv;
    m[1] = (2.0f * (x * y - z)) * inv;
    m[2] = (2.0f * (x * z + y)) * inv;
    m[3] = (2.0f * (x * y + z)) * inv;
    m[4] = (d + 2.0f * y * y) * inv;
    m[5] = (2.0f * (y * z - x)) * inv;
    m[6] = (2.0f * (x * z - y)) * inv;
    m[7] = (2.0f * (y * z + x)) * inv;
    m[8] = (d + 2.0f * z * z) * inv;
}

// Block = 256 threads x 4 points = 1024 points.
// Input span: 768 f4. Output span: 2304 f4 = 36 KB LDS -> 4 blocks/CU.
extern "C" __global__ __launch_bounds__(256)
void cayley_kernel(const float* __restrict__ t, float* __restrict__ out, int npts) {
    __shared__ f4 lds[2304];
    const int tid = threadIdx.x;
    const long in4_total  = (long)npts * 3 / 4;   // npts % 4 == 0 (N=4e6)
    const long out4_total = (long)npts * 9 / 4;
    const long inBase  = (long)blockIdx.x * 768;
    const long outBase = (long)blockIdx.x * 2304;

    // load 4 points (3 f4 per thread, 48B lane stride — measured ~ideal FETCH)
    const f4* in4 = (const f4*)t;
    float f[12];
    #pragma unroll
    for (int i = 0; i < 3; ++i) {
        const long idx = inBase + (long)tid * 3 + i;
        f4 v = (idx < in4_total) ? __builtin_nontemporal_load(in4 + idx)
                                 : (f4){0.f, 0.f, 0.f, 0.f};
        f[4 * i + 0] = v.x; f[4 * i + 1] = v.y;
        f[4 * i + 2] = v.z; f[4 * i + 3] = v.w;
    }

    // compute 4 matrices (36 floats), fully unrolled static indexing
    float m[36];
    #pragma unroll
    for (int i = 0; i < 4; ++i)
        cayley(f[3 * i + 0], f[3 * i + 1], f[3 * i + 2], &m[9 * i]);

    // stage to LDS (write side: 8-way bank alias, hidden; read side stride-1)
    #pragma unroll
    for (int k = 0; k < 9; ++k) {
        f4 v;
        v.x = m[4 * k + 0]; v.y = m[4 * k + 1];
        v.z = m[4 * k + 2]; v.w = m[4 * k + 3];
        lds[tid * 9 + k] = v;
    }
    __syncthreads();

    // coalesced output: wave instruction k writes 4 KB contiguous
    f4* o4 = (f4*)out;
    #pragma unroll
    for (int k = 0; k < 9; ++k) {
        const long idx = outBase + tid + 256 * k;
        if (idx < out4_total)
            __builtin_nontemporal_store(lds[tid + 256 * k], o4 + idx);
    }
}

extern "C" void kernel_launch(void* const* d_in, const int* in_sizes, int n_in,
                              void* d_out, int out_size, void* d_ws, size_t ws_size,
                              hipStream_t stream) {
    const float* t = (const float*)d_in[0];
    float* out = (float*)d_out;
    const int npts = in_sizes[0] / 3;
    const int blocks = (npts + 1023) / 1024;
    cayley_kernel<<<blocks, 256, 0, stream>>>(t, out, npts);
}

// Round 15
// 174.540 us; speedup vs baseline: 2.6412x; 1.0297x over previous
//
#include <hip/hip_runtime.h>

// Cayley map: R = ((1-s)I + 2A + 2 v v^T)/(1+s), s=|v|^2. N=4e6 fp32 points.
// Memory-bound: 48 MB read + 144 MB write -> ~31 us roofline @ 6.3 TB/s.
// R11: scatter nt stores -> 2.9x write amplification, 336 us.
// R14: LDS-staged coalesced nt stores -> kernel ~55 us (inferred; <88 us fills).
// This round: CACHED stores (drop nt) — harness fill sustains 6.5 TB/s via
// cached full-line write-back with WRITE_SIZE exactly 1.0x, so cached
// full-sector stores don't amplify; tests whether the nt/direct-HBM write
// path was throttling vs L2 write-back eviction.

typedef float f4 __attribute__((ext_vector_type(4)));

__device__ __forceinline__ void cayley(float x, float y, float z, float* m) {
    float s   = x * x + y * y + z * z;
    float inv = 1.0f / (1.0f + s);
    float d   = 1.0f - s;
    m[0] = (d + 2.0f * x * x) * inv;
    m[1] = (2.0f * (x * y - z)) * inv;
    m[2] = (2.0f * (x * z + y)) * inv;
    m[3] = (2.0f * (x * y + z)) * inv;
    m[4] = (d + 2.0f * y * y) * inv;
    m[5] = (2.0f * (y * z - x)) * inv;
    m[6] = (2.0f * (x * z - y)) * inv;
    m[7] = (2.0f * (y * z + x)) * inv;
    m[8] = (d + 2.0f * z * z) * inv;
}

// Block = 256 threads x 4 points = 1024 points.
// Input span: 768 f4. Output span: 2304 f4 = 36 KB LDS -> 4 blocks/CU.
extern "C" __global__ __launch_bounds__(256)
void cayley_kernel(const float* __restrict__ t, float* __restrict__ out, int npts) {
    __shared__ f4 lds[2304];
    const int tid = threadIdx.x;
    const long in4_total  = (long)npts * 3 / 4;   // npts % 4 == 0 (N=4e6)
    const long out4_total = (long)npts * 9 / 4;
    const long inBase  = (long)blockIdx.x * 768;
    const long outBase = (long)blockIdx.x * 2304;

    // load 4 points (3 f4 per thread, 48B lane stride — measured ~ideal FETCH)
    const f4* in4 = (const f4*)t;
    float f[12];
    #pragma unroll
    for (int i = 0; i < 3; ++i) {
        const long idx = inBase + (long)tid * 3 + i;
        f4 v = (idx < in4_total) ? __builtin_nontemporal_load(in4 + idx)
                                 : (f4){0.f, 0.f, 0.f, 0.f};
        f[4 * i + 0] = v.x; f[4 * i + 1] = v.y;
        f[4 * i + 2] = v.z; f[4 * i + 3] = v.w;
    }

    // compute 4 matrices (36 floats), fully unrolled static indexing
    float m[36];
    #pragma unroll
    for (int i = 0; i < 4; ++i)
        cayley(f[3 * i + 0], f[3 * i + 1], f[3 * i + 2], &m[9 * i]);

    // stage to LDS (b128 write: 2-way bank alias within 16-lane phase = free;
    // read side lane-consecutive = conflict-free)
    #pragma unroll
    for (int k = 0; k < 9; ++k) {
        f4 v;
        v.x = m[4 * k + 0]; v.y = m[4 * k + 1];
        v.z = m[4 * k + 2]; v.w = m[4 * k + 3];
        lds[tid * 9 + k] = v;
    }
    __syncthreads();

    // coalesced output: wave instruction k writes 1 KB/wave, 4 KB/block-inst
    // contiguous; CACHED stores (full dirty lines -> write-back, no RMW).
    f4* o4 = (f4*)out;
    #pragma unroll
    for (int k = 0; k < 9; ++k) {
        const long idx = outBase + tid + 256 * k;
        if (idx < out4_total)
            o4[idx] = lds[tid + 256 * k];
    }
}

extern "C" void kernel_launch(void* const* d_in, const int* in_sizes, int n_in,
                              void* d_out, int out_size, void* d_ws, size_t ws_size,
                              hipStream_t stream) {
    const float* t = (const float*)d_in[0];
    float* out = (float*)d_out;
    const int npts = in_sizes[0] / 3;
    const int blocks = (npts + 1023) / 1024;
    cayley_kernel<<<blocks, 256, 0, stream>>>(t, out, npts);
}